// Round 10
// baseline (184.865 us; speedup 1.0000x reference)
//
#include <hip/hip_runtime.h>
#include <math.h>

// Match numpy (no FMA contraction) — mask boundary is bit-sensitive.
#pragma clang fp contract(off)

namespace {

constexpr int B = 12, H = 192, W = 640;
constexpr int HW  = H * W;        // 122880
constexpr int BHW = B * HW;       // 1474560
constexpr int NQ  = BHW / 4;      // 368640 quads
constexpr float EPS = 1e-7f;

constexpr int TPB    = 1024;
constexpr int GRID   = 384;       // 16 waves/block @ launch_bounds(1024,8):
                                  // 2 blocks/CU * 256 CU = 512 slots >= 384
                                  // -> all blocks co-resident (manual barrier safe)
constexpr int QPB    = NQ / GRID; // 960 active quads/block (1 idle wave in A/B/C)
constexpr int TR     = 6;
constexpr int TILES  = H / TR;    // 32
constexpr int TRW    = TR * W;    // 3840 (block bi's sources ARE tile sblk of batch b)
constexpr int SBLK   = 32;        // source blocks per batch
constexpr int SEGCAP = TRW;       // 3840: one block can't emit more per tile

// ws: redA[GRID*4] @ +0 | redB[GRID*2] @ +8192 | bars[2] u32 @ +12288 |
//     cntA[B*TILES*SBLK] @ +16384 (48 KB) |
//     bkt[B*TILES*SBLK*SEGCAP] u32 @ +65536 (188.7 MB; ws = 256 MiB)
//
// Single persistent kernel (plain launch — R8's hipLaunchCooperativeKernel
// failed under graph capture; outputs stayed memset-zero). Manual grid
// barrier: release __threadfence (L2 writeback) -> atomicAdd arrive ->
// device-scope atomic spin -> acquire __threadfence. Co-residency is
// guaranteed by the launch_bounds/LDS math above; a clock64-bounded spin
// escape turns any residency violation into a visible absmax failure
// instead of a hang.
// Phases: A (read inputs once: mins->redA, bins->bkt/cntA, keep sx/sy in
// REGISTERS) | bar0 | B (reduce redA; re-load fx/fy — L2-hot, same XCD;
// check -> cva REGISTERS, partials->redB) | bar1 | C (reduce redB; mask
// from cva) | W (winner resolve, XCD-swizzled bucket, no barrier needed:
// bins complete since bar0, nobody reads winner outputs).
// Winner semantics: LWW == max-index-wins via LDS atomicMax(key=(n<<1|seg)+1)
// — bit-exact across R0-R9. min/max exactly associative => regrouped
// reductions bit-identical. All float arithmetic byte-identical to R9.

__device__ __forceinline__ void computeP(const float* __restrict__ Kb,
                                         const float* __restrict__ Po, float* P) {
#pragma unroll
    for (int i = 0; i < 3; ++i)
#pragma unroll
        for (int j = 0; j < 4; ++j) {
            float s = Kb[i*4+0] * Po[0*4+j];
            s = s + Kb[i*4+1] * Po[1*4+j];
            s = s + Kb[i*4+2] * Po[2*4+j];
            s = s + Kb[i*4+3] * Po[3*4+j];
            P[i*4+j] = s;
        }
}

__device__ __forceinline__ void static_flow_P(
    const float* __restrict__ iK, const float* __restrict__ P,
    int x, int y, float d, float& sx, float& sy)
{
    float fx = (float)x, fy = (float)y;
    float cam0 = iK[0]*fx + iK[1]*fy + iK[2];
    float cam1 = iK[4]*fx + iK[5]*fy + iK[6];
    float cam2 = iK[8]*fx + iK[9]*fy + iK[10];
    cam0 = d * cam0; cam1 = d * cam1; cam2 = d * cam2;
    float cp0 = P[0]*cam0 + P[1]*cam1 + P[2]*cam2  + P[3];
    float cp1 = P[4]*cam0 + P[5]*cam1 + P[6]*cam2  + P[7];
    float cp2 = P[8]*cam0 + P[9]*cam1 + P[10]*cam2 + P[11];
    float pz = cp2 + EPS;
    sx = cp0 / pz - fx;
    sy = cp1 / pz - fy;
}

__device__ __forceinline__ float norm01(float v, float mn, float mx) {
    return (2.0f * (v - mn)) / (mx - mn) - 1.0f;
}

__device__ __forceinline__ void blockRed4(float& a0, float& a1, float& a2, float& a3,
                                          float (*sred)[4], float* bc) {
    for (int off = 32; off; off >>= 1) {
        a0 = fminf(a0, __shfl_down(a0, off, 64));
        a1 = fmaxf(a1, __shfl_down(a1, off, 64));
        a2 = fminf(a2, __shfl_down(a2, off, 64));
        a3 = fmaxf(a3, __shfl_down(a3, off, 64));
    }
    int lane = threadIdx.x & 63, wv = threadIdx.x >> 6;
    if (lane == 0) { sred[wv][0]=a0; sred[wv][1]=a1; sred[wv][2]=a2; sred[wv][3]=a3; }
    __syncthreads();
    if (threadIdx.x == 0) {
#pragma unroll
        for (int w = 1; w < 16; ++w) {
            a0 = fminf(a0, sred[w][0]); a1 = fmaxf(a1, sred[w][1]);
            a2 = fminf(a2, sred[w][2]); a3 = fmaxf(a3, sred[w][3]);
        }
        bc[0]=a0; bc[1]=a1; bc[2]=a2; bc[3]=a3;
    }
    __syncthreads();
    a0=bc[0]; a1=bc[1]; a2=bc[2]; a3=bc[3];
}

__device__ __forceinline__ void blockRed2(float& a0, float& a1,
                                          float (*sred)[4], float* bc) {
    for (int off = 32; off; off >>= 1) {
        a0 = fminf(a0, __shfl_down(a0, off, 64));
        a1 = fmaxf(a1, __shfl_down(a1, off, 64));
    }
    int lane = threadIdx.x & 63, wv = threadIdx.x >> 6;
    if (lane == 0) { sred[wv][0]=a0; sred[wv][1]=a1; }
    __syncthreads();
    if (threadIdx.x == 0) {
#pragma unroll
        for (int w = 1; w < 16; ++w) {
            a0 = fminf(a0, sred[w][0]); a1 = fmaxf(a1, sred[w][1]);
        }
        bc[0]=a0; bc[1]=a1;
    }
    __syncthreads();
    a0=bc[0]; a1=bc[1];
}

// Manual grid barrier: release-fence, arrive, device-scope spin, acquire-fence.
// clock64 escape (~160ms) converts any co-residency violation into a visible
// wrong-answer instead of a hang.
__device__ __forceinline__ void gridBar(unsigned* bar) {
    __syncthreads();
    if (threadIdx.x == 0) {
        __threadfence();                       // writeback L2 (release)
        atomicAdd(bar, 1u);
        long long t0 = clock64();
        while (atomicAdd(bar, 0u) < (unsigned)GRID) {
            __builtin_amdgcn_s_sleep(16);
            if (clock64() - t0 > 400000000LL) break;
        }
        __threadfence();                       // invalidate (acquire)
    }
    __syncthreads();
}

__global__ void kInit(unsigned* __restrict__ bars) {
    if (threadIdx.x < 2) bars[threadIdx.x] = 0u;
}

__global__ void __launch_bounds__(TPB, 8)    // VGPR<=64 -> 2 blocks/CU guaranteed
kFused(const float* __restrict__ flow, const float* __restrict__ depth,
       const float* __restrict__ Km, const float* __restrict__ invK,
       const float* __restrict__ pose, const int* __restrict__ seg,
       unsigned* __restrict__ cntA, unsigned* __restrict__ bkt,
       float* __restrict__ redA, float* __restrict__ redB,
       unsigned* __restrict__ bars, float* __restrict__ out)
{
    __shared__ unsigned smem[TRW];           // 15360 B winner tile (phase W only)
    __shared__ float sred[16][4];
    __shared__ float bc[4];
    __shared__ unsigned tcnt[TILES];

    const int tid  = threadIdx.x;
    const int bi   = blockIdx.x;
    const int b    = bi >> 5;                // batch
    const int sblk = bi & 31;                // source tile within batch
    const bool act = tid < QPB;
    const int n0   = sblk * TRW + tid * 4;   // batch-local pixel base (if act)

    if (tid < TILES) tcnt[tid] = 0u;
    __syncthreads();

    // ================= Phase A: inputs once, mins, bins =================
    float sxa[4], sya[4], cva[4];
    float fmn = INFINITY, fmx = -INFINITY, smn = INFINITY, smx = -INFINITY;
    if (act) {
        float P[12];
        computeP(Km + b*16, pose + b*16, P);
        const float* iK = invK + b * 16;
        int y  = n0 / W;                     // quads never cross a row
        int x0 = n0 - y * W;
        float4 fx4 = *(const float4*)(flow + b*2*HW + n0);
        float4 fy4 = *(const float4*)(flow + b*2*HW + HW + n0);
        float4 d4  = *(const float4*)(depth + b*HW + n0);
        int4   s4  = *(const int4*)(seg + b*HW + n0);
        float fxa[4] = {fx4.x, fx4.y, fx4.z, fx4.w};
        float fya[4] = {fy4.x, fy4.y, fy4.z, fy4.w};
        float da[4]  = {d4.x, d4.y, d4.z, d4.w};
        int   sa[4]  = {s4.x, s4.y, s4.z, s4.w};
#pragma unroll
        for (int j = 0; j < 4; ++j) {
            fmn = fminf(fmn, fminf(fxa[j], fya[j]));
            fmx = fmaxf(fmx, fmaxf(fxa[j], fya[j]));
            float sx, sy;
            static_flow_P(iK, P, x0 + j, y, da[j], sx, sy);
            sxa[j] = sx; sya[j] = sy;
            smn = fminf(smn, fminf(sx, sy));
            smx = fmaxf(smx, fmaxf(sx, sy));
            // round-half-even (rintf == jnp.round), clip
            int cxi = (int)rintf((float)(x0 + j) + fxa[j]);
            int cyi = (int)rintf((float)y + fya[j]);
            cxi = min(max(cxi, 0), W - 1);
            cyi = min(max(cyi, 0), H - 1);
            int t   = cyi / TR;
            int pos = (cyi - t * TR) * W + cxi;                  // 12 bits
            unsigned ns = ((unsigned)(n0 + j) << 1) | (sa[j] ? 1u : 0u);
            unsigned e  = (ns << 12) | (unsigned)pos;
            unsigned r  = atomicAdd(&tcnt[t], 1u);
            bkt[((size_t)((b * TILES + t) * SBLK + sblk)) * SEGCAP + r] = e;
        }
    }
    blockRed4(fmn, fmx, smn, smx, sred, bc);    // internal syncthreads covers tcnt
    if (tid < TILES) cntA[(b * TILES + tid) * SBLK + sblk] = tcnt[tid];
    if (tid == 0) {
        redA[bi*4+0] = fmn; redA[bi*4+1] = fmx;
        redA[bi*4+2] = smn; redA[bi*4+3] = smx;
    }
    gridBar(&bars[0]);

    // ================= Phase B: check (re-load fx/fy, L2-hot) =================
    float gfmn = INFINITY, gfmx = -INFINITY, gsmn = INFINITY, gsmx = -INFINITY;
    if (tid < GRID) {
        gfmn = redA[tid*4+0]; gfmx = redA[tid*4+1];
        gsmn = redA[tid*4+2]; gsmx = redA[tid*4+3];
    }
    blockRed4(gfmn, gfmx, gsmn, gsmx, sred, bc);

    float cmn = INFINITY, cmx = -INFINITY;
    if (act) {
        float4 fx4 = *(const float4*)(flow + b*2*HW + n0);
        float4 fy4 = *(const float4*)(flow + b*2*HW + HW + n0);
        float fxa[4] = {fx4.x, fx4.y, fx4.z, fx4.w};
        float fya[4] = {fy4.x, fy4.y, fy4.z, fy4.w};
#pragma unroll
        for (int j = 0; j < 4; ++j) {
            float dx = norm01(fxa[j], gfmn, gfmx) - norm01(sxa[j], gsmn, gsmx);
            float dy = norm01(fya[j], gfmn, gfmx) - norm01(sya[j], gsmn, gsmx);
            float c = sqrtf(dx*dx + dy*dy);
            cva[j] = c;
            cmn = fminf(cmn, c); cmx = fmaxf(cmx, c);
        }
    }
    blockRed2(cmn, cmx, sred, bc);
    if (tid == 0) { redB[bi*2] = cmn; redB[bi*2+1] = cmx; }
    gridBar(&bars[1]);

    // ================= Phase C: mask =================
    float gcmn = INFINITY, gcmx = -INFINITY;
    if (tid < GRID) { gcmn = redB[2*tid]; gcmx = redB[2*tid+1]; }
    blockRed2(gcmn, gcmx, sred, bc);

    if (act) {
        int p0 = bi * TRW + tid * 4;             // == b*HW + n0
        float4 m4;
        float* ma = (float*)&m4;
#pragma unroll
        for (int j = 0; j < 4; ++j) {
            float cn = (cva[j] - gcmn) / (gcmx - gcmn);
            ma[j] = (cn < 0.98f) ? 1.0f : 0.0f;
        }
        *(float4*)(out + p0) = m4;               // motion_mask
    }

    // ================= Phase W: winner resolve (XCD-swizzled) =================
    {
        const int xcd = bi & 7, k = bi >> 3;
        const int wp  = xcd * 48 + k;            // bijective [0,384)
        const int b2  = wp >> 5, t2 = wp & 31;

        for (int i = tid; i < TRW; i += TPB) smem[i] = 0u;
        __syncthreads();

        const int wv = tid >> 6, lane = tid & 63;
        const unsigned* cbase = cntA + (b2 * TILES + t2) * SBLK;
        const size_t bktBase = (size_t)(b2 * TILES + t2) * SBLK;
        for (int s = wv; s < SBLK; s += 16) {
            unsigned c = cbase[s];
            const unsigned* src = bkt + (bktBase + s) * SEGCAP;
            for (unsigned i = lane; i < c; i += 64) {
                unsigned e = src[i];
                atomicMax(&smem[e & 4095u], (e >> 12) + 1u);
            }
        }
        __syncthreads();

        const float* fb = flow + b2 * 2 * HW;
        const int nbase = t2 * TRW;
        for (int q = tid; q < TRW/4; q += TPB) {
            uint4 w4 = *(const uint4*)(smem + q*4);
            unsigned wa[4] = {w4.x, w4.y, w4.z, w4.w};
            float4 bx4, by4, sg4;
            float* bxa = (float*)&bx4;
            float* bya = (float*)&by4;
            float* sga = (float*)&sg4;
#pragma unroll
            for (int j = 0; j < 4; ++j) {
                float bx = 0.0f, by = 0.0f, sg = 0.0f;
                if (wa[j]) {
                    unsigned u = wa[j] - 1u;
                    int nw = (int)(u >> 1);
                    sg = (u & 1u) ? 1.0f : 0.0f;
                    bx = -fb[nw];
                    by = -fb[HW + nw];
                }
                bxa[j] = bx; bya[j] = by; sga[j] = sg;
            }
            int n = nbase + q * 4;
            *(float4*)(out + BHW + b2*2*HW + n)      = bx4;  // bwd_flow x
            *(float4*)(out + BHW + b2*2*HW + HW + n) = by4;  // bwd_flow y
            *(float4*)(out + 3*BHW + b2*HW + n)      = sg4;  // seg_ref
        }
    }
}

} // namespace

extern "C" void kernel_launch(void* const* d_in, const int* in_sizes, int n_in,
                              void* d_out, int out_size, void* d_ws, size_t ws_size,
                              hipStream_t stream) {
    const float* flow  = (const float*)d_in[0];
    const float* depth = (const float*)d_in[1];
    const float* Km    = (const float*)d_in[2];
    const float* invK  = (const float*)d_in[3];
    const float* pose  = (const float*)d_in[4];
    const int*   seg   = (const int*)d_in[5];
    float* out = (float*)d_out;

    float*    redA = (float*)d_ws;                           // 6 KB
    float*    redB = (float*)((char*)d_ws + 8192);           // 3 KB
    unsigned* bars = (unsigned*)((char*)d_ws + 12288);       // 2 u32
    unsigned* cntA = (unsigned*)((char*)d_ws + 16384);       // 48 KB
    unsigned* bkt  = (unsigned*)((char*)d_ws + 65536);       // 188.7 MB

    kInit <<<1,    64,  0, stream>>>(bars);
    kFused<<<GRID, TPB, 0, stream>>>(flow, depth, Km, invK, pose, seg,
                                     cntA, bkt, redA, redB, bars, out);
}